// Round 10
// baseline (81.223 us; speedup 1.0000x reference)
//
#include <hip/hip_runtime.h>
#include <cstddef>

#define EPS 1e-6f
constexpr float INV_SQRT_E = 0.6065306597126334f;  // exp(-0.5*THETA^2), THETA=1
typedef float v2f __attribute__((ext_vector_type(2)));

// LDS-issue-throughput-bound (model: ~26 LDS-cyc/px == measured 24 us).
// Fix: 2 adjacent pixels per thread + SPLIT float planes (sx, slg) so one
// ds_read_b64 serves one tap for BOTH pixels (b64 = 64 B/cyc vs b32 44 B/cyc,
// and half the instruction count). Odd tap offsets (D=3, odd mj — folded at
// compile time) fall back to 2x b32. Horizontal taps read float4 from packed
// {col_s, col_s2}. Block (32,8)=256 thr, tile 64x8, LDS 39,936 B -> 4
// blocks/CU = 16 waves/CU; 4096 blocks, dilation in fast z bits.
template <int D>
__device__ __forceinline__ void body(const float* __restrict__ x,
                                     float* __restrict__ out,
                                     char* smem, int bc, int H, int W)
{
    constexpr int PAD = D * D;
    constexpr int KS  = 2 * D + 1;
    constexpr int K   = KS * KS;
    constexpr int TW  = 64, TH = 8;
    constexpr int LW  = TW + 2 * PAD;   // even
    constexpr int LH  = TH + 2 * PAD;   // even
    constexpr int NE  = LH * LW;
    constexpr int NP  = NE / 2;
    constexpr float INVK = 1.0f / (float)K;
    constexpr float UNB  = (float)K / (float)(K - 1);

    float*  sx  = (float*)smem;                 // [LH*LW] v
    float*  slg = sx + NE;                      // [LH*LW] v*log(v+eps)
    float2* cs2 = (float2*)(slg + NE);          // [TH*LW] {col_s, col_s2}
    float*  cs1 = (float*)(cs2 + TH * LW);      // [TH*LW] col_sl

    const int w0 = blockIdx.x * TW;
    const int h0 = blockIdx.y * TH;
    const float* xp = x + (size_t)bc * H * W;
    const int tid = threadIdx.y * 32 + threadIdx.x;

    // Staging: element PAIRS (LW even -> pairs never straddle rows).
    for (int e = tid; e < NP; e += 256) {
        const int i0 = 2 * e;
        const int r  = i0 / LW;
        const int c  = i0 - r * LW;
        const int gh = h0 - PAD + r;
        const int gw = w0 - PAD + c;
        float v0 = 0.f, v1 = 0.f;
        if (gh >= 0 && gh < H) {
            if (gw >= 0 && gw < W)     v0 = xp[gh * W + gw];
            if (gw + 1 >= 0 && gw + 1 < W) v1 = xp[gh * W + gw + 1];
        }
        *(float2*)(sx + i0)  = make_float2(v0, v1);
        *(float2*)(slg + i0) = make_float2(v0 * __logf(v0 + EPS),
                                           v1 * __logf(v1 + EPS));
    }
    __syncthreads();

    const int tx = threadIdx.x, ty = threadIdx.y;
    const int c0 = 2 * tx;                       // this thread's 2 pixel cols

    float sA, sB, s2A, s2B, slA, slB, sadA, sadB;

    if constexpr (D == 1) {
        // Register path: rows ty..ty+2, cols c0..c0+3 (6 b64 sx + 6 b64 slg).
        float ta[3][4];
        sA = sB = s2A = s2B = slA = slB = 0.f;
        #pragma unroll
        for (int mi = 0; mi < 3; ++mi) {
            const float* rp = sx  + (ty + mi) * LW + c0;
            const float* lp = slg + (ty + mi) * LW + c0;
            const float2 a  = *(const float2*)rp;
            const float2 b  = *(const float2*)(rp + 2);
            const float2 la = *(const float2*)lp;
            const float2 lb = *(const float2*)(lp + 2);
            ta[mi][0] = a.x; ta[mi][1] = a.y; ta[mi][2] = b.x; ta[mi][3] = b.y;
            sA += a.x + a.y + b.x;      sB += a.y + b.x + b.y;
            s2A = fmaf(a.x, a.x, s2A); s2A = fmaf(a.y, a.y, s2A); s2A = fmaf(b.x, b.x, s2A);
            s2B = fmaf(a.y, a.y, s2B); s2B = fmaf(b.x, b.x, s2B); s2B = fmaf(b.y, b.y, s2B);
            slA += la.x + la.y + lb.x;  slB += la.y + lb.x + lb.y;
        }
        const float muA = sA * INVK, muB = sB * INVK;
        sadA = sadB = 0.f;
        #pragma unroll
        for (int mi = 0; mi < 3; ++mi)
            #pragma unroll
            for (int mj = 0; mj < 3; ++mj) {
                sadA += fabsf(ta[mi][mj]     - muA);
                sadB += fabsf(ta[mi][mj + 1] - muB);
            }
    } else {
        // Vertical: column sums over KS row taps, column-PAIR per iter.
        constexpr int NCP = TH * LW / 2;
        for (int e = tid; e < NCP; e += 256) {
            const int i0 = 2 * e;
            const int r  = i0 / LW;
            const int c  = i0 - r * LW;
            const float* cx = sx  + r * LW + c;
            const float* cl = slg + r * LW + c;
            float vs0 = 0, vs1 = 0, vq0 = 0, vq1 = 0, vl0 = 0, vl1 = 0;
            #pragma unroll
            for (int mi = 0; mi < KS; ++mi) {
                const float2 p = *(const float2*)(cx + mi * D * LW);
                const float2 q = *(const float2*)(cl + mi * D * LW);
                vs0 += p.x; vs1 += p.y;
                vq0 = fmaf(p.x, p.x, vq0); vq1 = fmaf(p.y, p.y, vq1);
                vl0 += q.x; vl1 += q.y;
            }
            *(float4*)(cs2 + i0) = make_float4(vs0, vq0, vs1, vq1);
            *(float2*)(cs1 + i0) = make_float2(vl0, vl1);
        }
        __syncthreads();

        // Horizontal: KS taps; float4 covers both pixels' {s,s2} when o even.
        sA = sB = s2A = s2B = slA = slB = 0.f;
        const float2* h2 = cs2 + ty * LW + c0;
        const float*  h1 = cs1 + ty * LW + c0;
        #pragma unroll
        for (int mj = 0; mj < KS; ++mj) {
            const int o = mj * D;                // parity folds at compile time
            float2 e0, e1, l;
            if ((o & 1) == 0) {
                const float4 A = *(const float4*)(h2 + o);
                e0 = make_float2(A.x, A.y); e1 = make_float2(A.z, A.w);
                l  = *(const float2*)(h1 + o);
            } else {
                e0 = h2[o]; e1 = h2[o + 1];
                l  = make_float2(h1[o], h1[o + 1]);
            }
            sA += e0.x; s2A += e0.y; sB += e1.x; s2B += e1.y;
            slA += l.x; slB += l.y;
        }
        const float muA = sA * INVK, muB = sB * INVK;

        // SAD: one b64 per tap serves both pixels (2x b32 when o odd).
        sadA = sadB = 0.f;
        const float* bp = sx + ty * LW + c0;
        #pragma unroll
        for (int mi = 0; mi < KS; ++mi) {
            const float* rp = bp + mi * D * LW;
            #pragma unroll
            for (int mj = 0; mj < KS; ++mj) {
                const int o = mj * D;
                float2 t;
                if ((o & 1) == 0) t = *(const float2*)(rp + o);
                else              t = make_float2(rp[o], rp[o + 1]);
                sadA += fabsf(t.x - muA);
                sadB += fabsf(t.y - muB);
            }
        }
    }

    // Epilogue: 2 px x 4 features, float2 nontemporal stores.
    const size_t fs = (size_t)H * W;
    const size_t ro = (size_t)(h0 + ty) * W + c0;
    float* op = out + (size_t)bc * 4 * fs + w0;
    const float muA = sA * INVK,  muB = sB * INVK;
    const float enA = s2A * INVK, enB = s2B * INVK;
    const float vaA = fmaxf(enA - muA * muA, 0.f), vaB = fmaxf(enB - muB * muB, 0.f);
    const float sdA = sqrtf(vaA * UNB) + EPS,      sdB = sqrtf(vaB * UNB) + EPS;
    const float coA = vaA / (sdA * sdA),           coB = vaB / (sdB * sdB);
    const float etA = -slA * INVK,                 etB = -slB * INVK;
    const float hoA = 1.f / (1.f + sadA * INVK),   hoB = 1.f / (1.f + sadB * INVK);
    v2f t;
    t = (v2f){(coA + EPS) * INV_SQRT_E, (coB + EPS) * INV_SQRT_E};
    __builtin_nontemporal_store(t, (v2f*)(op + 0 * fs + ro));
    t = (v2f){(enA + EPS) * INV_SQRT_E, (enB + EPS) * INV_SQRT_E};
    __builtin_nontemporal_store(t, (v2f*)(op + 1 * fs + ro));
    t = (v2f){(etA + EPS) * INV_SQRT_E, (etB + EPS) * INV_SQRT_E};
    __builtin_nontemporal_store(t, (v2f*)(op + 2 * fs + ro));
    t = (v2f){(hoA + EPS) * INV_SQRT_E, (hoB + EPS) * INV_SQRT_E};
    __builtin_nontemporal_store(t, (v2f*)(op + 3 * fs + ro));
}

__global__ __launch_bounds__(256, 4) void tex_fused(
    const float* __restrict__ x, float* __restrict__ out, int H, int W)
{
    extern __shared__ __align__(16) char smem[];
    const int dz = blockIdx.z & 3;       // dilation in fast bits: co-resident
    const int bc = blockIdx.z >> 2;      // blocks on a CU mix D1..D4
    const size_t per = (size_t)8 * 4 * H * W;
    switch (dz) {
        case 0: body<4>(x, out + 3 * per, smem, bc, H, W); break;
        case 1: body<3>(x, out + 2 * per, smem, bc, H, W); break;
        case 2: body<2>(x, out + 1 * per, smem, bc, H, W); break;
        default: body<1>(x, out + 0 * per, smem, bc, H, W); break;
    }
}

extern "C" void kernel_launch(void* const* d_in, const int* in_sizes, int n_in,
                              void* d_out, int out_size, void* d_ws, size_t ws_size,
                              hipStream_t stream) {
    const float* x = (const float*)d_in[0];
    float* out = (float*)d_out;

    const int H = 256, W = 256;
    // Per-D LDS (TH=8, PAD=D*D): 2 float planes LH*LW*8 + cs TH*LW*12
    //   D=4: LH=40, LW=96: 30720 + 9216 = 39936  (max) -> 4 blocks/CU
    //   D=3: LH=26, LW=82: 17056 + 7872 = 24928
    //   D=2: LH=16, LW=72:  9216 + 6912 = 16128
    //   D=1: LH=10, LW=66:  5280 (register path)
    const size_t smem_bytes = 39936;

    dim3 blk(32, 8, 1);
    dim3 grd(W / 64, H / 8, 8 * 4);      // 4 x-tiles, 32 y-tiles, (bc x dz)
    tex_fused<<<grd, blk, smem_bytes, stream>>>(x, out, H, W);
}